// Round 4
// baseline (158.097 us; speedup 1.0000x reference)
//
#include <hip/hip_runtime.h>
#include <stdint.h>

#define BI 128
#define BT 128
#define RR 36
#define WW 50
#define DD 1024
#define NN 6400       /* fg row stride, static */
#define SEPS 1e-6f

typedef __attribute__((ext_vector_type(8))) short short8v;
typedef __attribute__((ext_vector_type(4))) float float4v;
typedef __attribute__((ext_vector_type(2))) unsigned int uint2v;

__device__ __forceinline__ unsigned short f2bf(float f){
  unsigned u = __float_as_uint(f);
  return (unsigned short)((u + 0x7FFFu + ((u >> 16) & 1u)) >> 16);
}

// ---- exclusive prefix scan of il (128) and cl (128); dst[128] = total ----
__global__ __launch_bounds__(256) void prefix_kernel(
    const int* __restrict__ il, const int* __restrict__ cl,
    int* __restrict__ rowoff, int* __restrict__ coloff){
  __shared__ int buf[2][128];
  const int t = threadIdx.x;
  const int which = t >> 7, j = t & 127;
  const int v = which ? cl[j] : il[j];
  buf[which][j] = v;
  __syncthreads();
  #pragma unroll
  for (int off = 1; off < 128; off <<= 1){
    int x = (j >= off) ? buf[which][j - off] : 0;
    __syncthreads();
    buf[which][j] += x;
    __syncthreads();
  }
  int* dst = which ? coloff : rowoff;
  dst[j] = buf[which][j] - v;                 // exclusive
  if (j == 127) dst[128] = buf[which][127];   // total (M' / N')
}

// ---- gather valid rows + f32->bf16 convert. Block = one source row. ----
__global__ __launch_bounds__(256) void gather_cvt_kernel(
    const float* __restrict__ imgs, const float* __restrict__ caps,
    const int* __restrict__ il, const int* __restrict__ cl,
    const int* __restrict__ rowoff, const int* __restrict__ coloff,
    unsigned short* __restrict__ Ab, unsigned short* __restrict__ Bb){
  const int b = blockIdx.x;
  const int t = threadIdx.x;
  if (b < BI * RR){
    const int i = b / RR, r = b % RR;
    if (r >= il[i]) return;
    const float4 v = *(const float4*)(imgs + (size_t)b * DD + t * 4);
    ushort4 o = make_ushort4(f2bf(v.x), f2bf(v.y), f2bf(v.z), f2bf(v.w));
    *(ushort4*)(Ab + (size_t)(rowoff[i] + r) * DD + t * 4) = o;
  } else {
    const int bb = b - BI * RR;
    const int c = bb / WW, w = bb % WW;
    if (w >= cl[c]) return;
    const float4 v = *(const float4*)(caps + (size_t)bb * DD + t * 4);
    ushort4 o = make_ushort4(f2bf(v.x), f2bf(v.y), f2bf(v.z), f2bf(v.w));
    *(ushort4*)(Bb + (size_t)(coloff[c] + w) * DD + t * 4) = o;
  }
}

// ---- m97-structure 128x128x64 GEMM over compacted rows; early-exit tiles ----
__global__ __launch_bounds__(256) void gemm_kernel(
    const unsigned short* __restrict__ A, const unsigned short* __restrict__ B,
    const int* __restrict__ rowoff, const int* __restrict__ coloff,
    float* __restrict__ C){
  __shared__ __align__(16) unsigned char LDS[32768];
  const int bx = blockIdx.x;
  const int swz = (bx & 7) * 225 + (bx >> 3);     // 1800 = 8*225, bijective
  const int mb = swz / 50, nb = swz % 50;
  const int m0 = mb * 128, n0 = nb * 128;
  const int Mp = rowoff[BI];                      // M' (runtime)
  const int Np = coloff[BT];                      // N'
  if (m0 >= Mp || n0 >= Np) return;               // uniform early-exit

  const int tid = threadIdx.x;
  const int lane = tid & 63, wv = tid >> 6;
  const int l15 = lane & 15, lhi = lane >> 4;
  const int wr = wv >> 1, wc = wv & 1;            // 2x2 wave grid, 64x64/wave

  const unsigned short* sA[4];
  const unsigned short* sB[4];
  #pragma unroll
  for (int j = 0; j < 4; j++){
    int u = j * 256 + tid;                        // 16B unit 0..1023
    int row = u >> 3;
    int kg = (u & 7) ^ (row & 7);                 // source pre-swizzle
    sA[j] = A + (size_t)(m0 + row) * DD + kg * 8;
    sB[j] = B + (size_t)(n0 + row) * DD + kg * 8;
  }

  float4v acc[4][4];
  #pragma unroll
  for (int a1 = 0; a1 < 4; a1++)
    #pragma unroll
    for (int b1 = 0; b1 < 4; b1++)
      acc[a1][b1] = (float4v){0.f, 0.f, 0.f, 0.f};

  for (int ch = 0; ch < 16; ch++){
    __syncthreads();
    #pragma unroll
    for (int j = 0; j < 4; j++){
      __builtin_amdgcn_global_load_lds(
          (const __attribute__((address_space(1))) void*)(sA[j] + ch * 64),
          (__attribute__((address_space(3))) void*)(LDS + (j * 256 + tid) * 16),
          16, 0, 0);
      __builtin_amdgcn_global_load_lds(
          (const __attribute__((address_space(1))) void*)(sB[j] + ch * 64),
          (__attribute__((address_space(3))) void*)(LDS + 16384 + (j * 256 + tid) * 16),
          16, 0, 0);
    }
    __syncthreads();
    #pragma unroll
    for (int s = 0; s < 2; s++){
      int kb = s * 4 + lhi;
      short8v af[4], bf[4];
      #pragma unroll
      for (int tr = 0; tr < 4; tr++){
        int row = wr * 64 + tr * 16 + l15;
        af[tr] = *(const short8v*)(LDS + (row * 8 + (kb ^ (row & 7))) * 16);
      }
      #pragma unroll
      for (int tw = 0; tw < 4; tw++){
        int row = wc * 64 + tw * 16 + l15;
        bf[tw] = *(const short8v*)(LDS + 16384 + (row * 8 + (kb ^ (row & 7))) * 16);
      }
      #pragma unroll
      for (int tr = 0; tr < 4; tr++)
        #pragma unroll
        for (int tw = 0; tw < 4; tw++)
          acc[tr][tw] = __builtin_amdgcn_mfma_f32_16x16x32_bf16(
              af[tr], bf[tw], acc[tr][tw], 0, 0, 0);
    }
  }

  // C/D layout: col = lane&15, row = lhi*4 + j (m89/m91, validated R1-R3)
  #pragma unroll
  for (int tr = 0; tr < 4; tr++)
    #pragma unroll
    for (int tw = 0; tw < 4; tw++)
      #pragma unroll
      for (int j = 0; j < 4; j++){
        int m = m0 + wr * 64 + tr * 16 + lhi * 4 + j;
        int n = n0 + wc * 64 + tw * 16 + l15;
        C[(size_t)m * NN + n] = acc[tr][tw][j];
      }
}

// ---- wave-wide sum: 4 DPP row_ror adds + 2 permlane swaps (pure VALU) ----
template<int CTRL>
__device__ __forceinline__ float dpp_add(float x){
  int y = __builtin_amdgcn_mov_dpp(__float_as_int(x), CTRL, 0xF, 0xF, true);
  return x + __int_as_float(y);
}
__device__ __forceinline__ float waveAllSum(float x){
  x = dpp_add<0x121>(x);   // row_ror:1
  x = dpp_add<0x122>(x);   // row_ror:2
  x = dpp_add<0x124>(x);   // row_ror:4
  x = dpp_add<0x128>(x);   // row_ror:8  -> every lane holds its 16-group sum S_g
#if __has_builtin(__builtin_amdgcn_permlane32_swap)
  {
    unsigned xi = __float_as_uint(x);
    uint2v r = __builtin_amdgcn_permlane32_swap(xi, xi, false, false);
    // r[0] = [S2,S3,S2,S3], r[1] = [S0,S1,S0,S1]  (per 16-group)
    x = __uint_as_float(r[0]) + __uint_as_float(r[1]);   // [S02,S13,S02,S13]
  }
#else
  x += __shfl_xor(x, 32);
#endif
#if __has_builtin(__builtin_amdgcn_permlane16_swap)
  {
    unsigned xi = __float_as_uint(x);
    uint2v r = __builtin_amdgcn_permlane16_swap(xi, xi, false, false);
    x = __uint_as_float(r[0]) + __uint_as_float(r[1]);   // S_all in every lane
  }
#else
  x += __shfl_xor(x, 16);
#endif
  return x;
}

// ---- per-wave Sinkhorn over compacted fg; lane = word w; rows pruned at ilen ----
__global__ __launch_bounds__(256) void sink_kernel(
    const float* __restrict__ fg, const int* __restrict__ il,
    const int* __restrict__ cl, const int* __restrict__ rowoff,
    const int* __restrict__ coloff, float* __restrict__ out){
  const int lane = threadIdx.x & 63;
  const int gw = blockIdx.x * 4 + (threadIdx.x >> 6);
  const int i = gw >> 7, c = gw & 127;
  // wave-uniform scalars -> SGPRs so per-row guards are scalar branches
  const int ilen = __builtin_amdgcn_readfirstlane(il[i]);
  const int clen = __builtin_amdgcn_readfirstlane(cl[c]);
  const int ro   = __builtin_amdgcn_readfirstlane(rowoff[i]);
  const int co   = __builtin_amdgcn_readfirstlane(coloff[c]);
  const float* base = fg + (size_t)ro * NN + co;
  const int w = lane;

  const float inv_il = __fdividef(1.0f, (float)ilen);
  const float inv_cl = __fdividef(1.0f, (float)clen);
  const bool vw = (w < clen);

  float f[RR], p[RR];
  float s0 = 0.f;
  #pragma unroll
  for (int r = 0; r < RR; r++){
    if (r < ilen){                                // uniform (SGPR) branch
      float fv = vw ? base[(size_t)r * NN + w] : 0.0f;
      f[r] = fv;
      p[r] = vw ? __expf(fv * 20.0f - 20.0f) : 0.0f;
      s0 += p[r];
    }
  }
  s0 = waveAllSum(s0);
  float sc = __fdividef(1.0f, s0 + SEPS);         // P /= (sum + EPS)
  #pragma unroll
  for (int r = 0; r < RR; r++)
    if (r < ilen) p[r] *= sc;

  for (int it = 0; it < 3; it++){
    #pragma unroll
    for (int r = 0; r < RR; r++){
      if (r < ilen){
        float t = waveAllSum(p[r]);               // u = rowsum + EPS
        p[r] *= __fdividef(inv_il, t + SEPS);
      }
    }
    float v = 0.f;                                // colsum (in-lane)
    #pragma unroll
    for (int r = 0; r < RR; r++)
      if (r < ilen) v += p[r];
    float cs = __fdividef(inv_cl, v + SEPS);
    #pragma unroll
    for (int r = 0; r < RR; r++)
      if (r < ilen) p[r] *= cs;
  }

  float sim = 0.f;
  #pragma unroll
  for (int r = 0; r < RR; r++)
    if (r < ilen) sim = fmaf(f[r], p[r], sim);
  sim = waveAllSum(sim);
  if (lane == 0) out[i * BT + c] = sim;
}

extern "C" void kernel_launch(void* const* d_in, const int* in_sizes, int n_in,
                              void* d_out, int out_size, void* d_ws, size_t ws_size,
                              hipStream_t stream){
  const float* imgs = (const float*)d_in[0];
  const float* caps = (const float*)d_in[1];
  const int* il = (const int*)d_in[2];
  const int* cl = (const int*)d_in[3];
  float* out = (float*)d_out;

  unsigned short* Ab = (unsigned short*)d_ws;               // [4608][1024] bf16
  unsigned short* Bb = Ab + (size_t)BI * RR * DD;           // [6400][1024] bf16
  float* fg = (float*)(Bb + (size_t)BT * WW * DD);          // [4608][6400] f32
  int* rowoff = (int*)(fg + (size_t)BI * RR * NN);          // [129]
  int* coloff = rowoff + 129;                               // [129]

  prefix_kernel<<<1, 256, 0, stream>>>(il, cl, rowoff, coloff);
  gather_cvt_kernel<<<BI * RR + BT * WW, 256, 0, stream>>>(
      imgs, caps, il, cl, rowoff, coloff, Ab, Bb);
  gemm_kernel<<<36 * 50, 256, 0, stream>>>(Ab, Bb, rowoff, coloff, fg);
  sink_kernel<<<(BI * BT) / 4, 256, 0, stream>>>(fg, il, cl, rowoff, coloff, out);
}

// Round 5
// 147.583 us; speedup vs baseline: 1.0712x; 1.0712x over previous
//
#include <hip/hip_runtime.h>
#include <stdint.h>

#define BI 128
#define BT 128
#define RR 36
#define WW 50
#define DD 1024
#define NN 6400       /* fg row stride, static */
#define SEPS 1e-6f

typedef __attribute__((ext_vector_type(8))) short short8v;
typedef __attribute__((ext_vector_type(4))) float float4v;
typedef __attribute__((ext_vector_type(2))) unsigned int uint2v;

__device__ __forceinline__ unsigned short f2bf(float f){
  unsigned u = __float_as_uint(f);
  return (unsigned short)((u + 0x7FFFu + ((u >> 16) & 1u)) >> 16);
}

// ---- exclusive prefix scan of il (128) and cl (128); dst[128] = total ----
__global__ __launch_bounds__(256) void prefix_kernel(
    const int* __restrict__ il, const int* __restrict__ cl,
    int* __restrict__ rowoff, int* __restrict__ coloff){
  __shared__ int buf[2][128];
  const int t = threadIdx.x;
  const int which = t >> 7, j = t & 127;
  const int v = which ? cl[j] : il[j];
  buf[which][j] = v;
  __syncthreads();
  #pragma unroll
  for (int off = 1; off < 128; off <<= 1){
    int x = (j >= off) ? buf[which][j - off] : 0;
    __syncthreads();
    buf[which][j] += x;
    __syncthreads();
  }
  int* dst = which ? coloff : rowoff;
  dst[j] = buf[which][j] - v;                 // exclusive
  if (j == 127) dst[128] = buf[which][127];   // total (M' / N')
}

// ---- gather valid rows + f32->bf16 convert. Block = one source row. ----
__global__ __launch_bounds__(256) void gather_cvt_kernel(
    const float* __restrict__ imgs, const float* __restrict__ caps,
    const int* __restrict__ il, const int* __restrict__ cl,
    const int* __restrict__ rowoff, const int* __restrict__ coloff,
    unsigned short* __restrict__ Ab, unsigned short* __restrict__ Bb){
  const int b = blockIdx.x;
  const int t = threadIdx.x;
  if (b < BI * RR){
    const int i = b / RR, r = b % RR;
    if (r >= il[i]) return;
    const float4 v = *(const float4*)(imgs + (size_t)b * DD + t * 4);
    ushort4 o = make_ushort4(f2bf(v.x), f2bf(v.y), f2bf(v.z), f2bf(v.w));
    *(ushort4*)(Ab + (size_t)(rowoff[i] + r) * DD + t * 4) = o;
  } else {
    const int bb = b - BI * RR;
    const int c = bb / WW, w = bb % WW;
    if (w >= cl[c]) return;
    const float4 v = *(const float4*)(caps + (size_t)bb * DD + t * 4);
    ushort4 o = make_ushort4(f2bf(v.x), f2bf(v.y), f2bf(v.z), f2bf(v.w));
    *(ushort4*)(Bb + (size_t)(coloff[c] + w) * DD + t * 4) = o;
  }
}

// ---- m97-structure 128x128x64 GEMM over compacted rows; early-exit tiles ----
__global__ __launch_bounds__(256) void gemm_kernel(
    const unsigned short* __restrict__ A, const unsigned short* __restrict__ B,
    const int* __restrict__ rowoff, const int* __restrict__ coloff,
    float* __restrict__ C){
  __shared__ __align__(16) unsigned char LDS[32768];
  const int bx = blockIdx.x;
  const int swz = (bx & 7) * 225 + (bx >> 3);     // 1800 = 8*225, bijective
  const int mb = swz / 50, nb = swz % 50;
  const int m0 = mb * 128, n0 = nb * 128;
  const int Mp = rowoff[BI];                      // M' (runtime)
  const int Np = coloff[BT];                      // N'
  if (m0 >= Mp || n0 >= Np) return;               // uniform early-exit

  const int tid = threadIdx.x;
  const int lane = tid & 63, wv = tid >> 6;
  const int l15 = lane & 15, lhi = lane >> 4;
  const int wr = wv >> 1, wc = wv & 1;            // 2x2 wave grid, 64x64/wave

  const unsigned short* sA[4];
  const unsigned short* sB[4];
  #pragma unroll
  for (int j = 0; j < 4; j++){
    int u = j * 256 + tid;                        // 16B unit 0..1023
    int row = u >> 3;
    int kg = (u & 7) ^ (row & 7);                 // source pre-swizzle
    sA[j] = A + (size_t)(m0 + row) * DD + kg * 8;
    sB[j] = B + (size_t)(n0 + row) * DD + kg * 8;
  }

  float4v acc[4][4];
  #pragma unroll
  for (int a1 = 0; a1 < 4; a1++)
    #pragma unroll
    for (int b1 = 0; b1 < 4; b1++)
      acc[a1][b1] = (float4v){0.f, 0.f, 0.f, 0.f};

  for (int ch = 0; ch < 16; ch++){
    __syncthreads();
    #pragma unroll
    for (int j = 0; j < 4; j++){
      __builtin_amdgcn_global_load_lds(
          (const __attribute__((address_space(1))) void*)(sA[j] + ch * 64),
          (__attribute__((address_space(3))) void*)(LDS + (j * 256 + tid) * 16),
          16, 0, 0);
      __builtin_amdgcn_global_load_lds(
          (const __attribute__((address_space(1))) void*)(sB[j] + ch * 64),
          (__attribute__((address_space(3))) void*)(LDS + 16384 + (j * 256 + tid) * 16),
          16, 0, 0);
    }
    __syncthreads();
    #pragma unroll
    for (int s = 0; s < 2; s++){
      int kb = s * 4 + lhi;
      short8v af[4], bf[4];
      #pragma unroll
      for (int tr = 0; tr < 4; tr++){
        int row = wr * 64 + tr * 16 + l15;
        af[tr] = *(const short8v*)(LDS + (row * 8 + (kb ^ (row & 7))) * 16);
      }
      #pragma unroll
      for (int tw = 0; tw < 4; tw++){
        int row = wc * 64 + tw * 16 + l15;
        bf[tw] = *(const short8v*)(LDS + 16384 + (row * 8 + (kb ^ (row & 7))) * 16);
      }
      #pragma unroll
      for (int tr = 0; tr < 4; tr++)
        #pragma unroll
        for (int tw = 0; tw < 4; tw++)
          acc[tr][tw] = __builtin_amdgcn_mfma_f32_16x16x32_bf16(
              af[tr], bf[tw], acc[tr][tw], 0, 0, 0);
    }
  }

  // C/D layout: col = lane&15, row = lhi*4 + j (m89/m91, validated R1-R4)
  #pragma unroll
  for (int tr = 0; tr < 4; tr++)
    #pragma unroll
    for (int tw = 0; tw < 4; tw++)
      #pragma unroll
      for (int j = 0; j < 4; j++){
        int m = m0 + wr * 64 + tr * 16 + lhi * 4 + j;
        int n = n0 + wc * 64 + tw * 16 + l15;
        C[(size_t)m * NN + n] = acc[tr][tw][j];
      }
}

// ---- wave-wide sum: 4 DPP row_ror adds + 2 permlane swaps (pure VALU) ----
template<int CTRL>
__device__ __forceinline__ float dpp_add(float x){
  int y = __builtin_amdgcn_mov_dpp(__float_as_int(x), CTRL, 0xF, 0xF, true);
  return x + __int_as_float(y);
}
__device__ __forceinline__ float waveAllSum(float x){
  x = dpp_add<0x121>(x);   // row_ror:1
  x = dpp_add<0x122>(x);   // row_ror:2
  x = dpp_add<0x124>(x);   // row_ror:4
  x = dpp_add<0x128>(x);   // row_ror:8  -> every lane holds its 16-group sum
#if __has_builtin(__builtin_amdgcn_permlane32_swap)
  {
    unsigned xi = __float_as_uint(x);
    uint2v r = __builtin_amdgcn_permlane32_swap(xi, xi, false, false);
    x = __uint_as_float(r[0]) + __uint_as_float(r[1]);
  }
#else
  x += __shfl_xor(x, 32);
#endif
#if __has_builtin(__builtin_amdgcn_permlane16_swap)
  {
    unsigned xi = __float_as_uint(x);
    uint2v r = __builtin_amdgcn_permlane16_swap(xi, xi, false, false);
    x = __uint_as_float(r[0]) + __uint_as_float(r[1]);
  }
#else
  x += __shfl_xor(x, 16);
#endif
  return x;
}

// ---- per-wave Sinkhorn; lane = word w; rows pruned in 9-row chunks ----
// __launch_bounds__(256, 1): allow high VGPR so p[36]+f[36] stay in registers
// (R3/R4 showed VGPR_Count=48..52 -> both arrays spilled to scratch).
#define CK 9
__global__ __launch_bounds__(256, 1) void sink_kernel(
    const float* __restrict__ fg, const int* __restrict__ il,
    const int* __restrict__ cl, const int* __restrict__ rowoff,
    const int* __restrict__ coloff, float* __restrict__ out){
  const int lane = threadIdx.x & 63;
  const int gw = blockIdx.x * 4 + (threadIdx.x >> 6);
  const int i = gw >> 7, c = gw & 127;
  const int ilen = __builtin_amdgcn_readfirstlane(il[i]);
  const int clen = cl[c];
  const int ro   = __builtin_amdgcn_readfirstlane(rowoff[i]);
  const int co   = __builtin_amdgcn_readfirstlane(coloff[c]);
  const float* base = fg + (size_t)ro * NN + co + lane;
  const float inv_il = __fdividef(1.0f, (float)ilen);
  const float inv_cl = __fdividef(1.0f, (float)clen);
  const bool vw = (lane < clen);

  float f[RR], p[RR];
  float s0 = 0.f;
  #pragma unroll
  for (int ck = 0; ck < 4; ck++){
    if (ck * CK < ilen){                          // wave-uniform chunk guard
      #pragma unroll
      for (int q = 0; q < CK; q++){
        const int r = ck * CK + q;
        const float fv = base[(size_t)r * NN];    // unpredicated (in-buffer)
        f[r] = fv;
        p[r] = (vw && r < ilen) ? __expf(fmaf(fv, 20.0f, -20.0f)) : 0.0f;
        s0 += p[r];
      }
    }
  }
  s0 = waveAllSum(s0);
  const float sc = __fdividef(1.0f, s0 + SEPS);   // P /= (sum + EPS)
  #pragma unroll
  for (int ck = 0; ck < 4; ck++){
    if (ck * CK < ilen){
      #pragma unroll
      for (int q = 0; q < CK; q++) p[ck * CK + q] *= sc;
    }
  }

  for (int it = 0; it < 3; it++){
    #pragma unroll
    for (int ck = 0; ck < 4; ck++){
      if (ck * CK < ilen){
        #pragma unroll
        for (int q = 0; q < CK; q++){             // u = rowsum + EPS; P *= r/u
          const int r = ck * CK + q;
          const float t = waveAllSum(p[r]);
          p[r] *= __fdividef(inv_il, t + SEPS);
        }
      }
    }
    float v = 0.f;                                // colsum (in-lane)
    #pragma unroll
    for (int ck = 0; ck < 4; ck++){
      if (ck * CK < ilen){
        #pragma unroll
        for (int q = 0; q < CK; q++) v += p[ck * CK + q];
      }
    }
    const float cs = __fdividef(inv_cl, v + SEPS);
    #pragma unroll
    for (int ck = 0; ck < 4; ck++){
      if (ck * CK < ilen){
        #pragma unroll
        for (int q = 0; q < CK; q++) p[ck * CK + q] *= cs;
      }
    }
  }

  float sim = 0.f;
  #pragma unroll
  for (int ck = 0; ck < 4; ck++){
    if (ck * CK < ilen){
      #pragma unroll
      for (int q = 0; q < CK; q++){
        const int r = ck * CK + q;
        sim = fmaf(f[r], p[r], sim);
      }
    }
  }
  sim = waveAllSum(sim);
  if (lane == 0) out[i * BT + c] = sim;
}

extern "C" void kernel_launch(void* const* d_in, const int* in_sizes, int n_in,
                              void* d_out, int out_size, void* d_ws, size_t ws_size,
                              hipStream_t stream){
  const float* imgs = (const float*)d_in[0];
  const float* caps = (const float*)d_in[1];
  const int* il = (const int*)d_in[2];
  const int* cl = (const int*)d_in[3];
  float* out = (float*)d_out;

  unsigned short* Ab = (unsigned short*)d_ws;               // [4608][1024] bf16
  unsigned short* Bb = Ab + (size_t)BI * RR * DD;           // [6400][1024] bf16
  float* fg = (float*)(Bb + (size_t)BT * WW * DD);          // [4608][6400] f32
  int* rowoff = (int*)(fg + (size_t)BI * RR * NN);          // [129]
  int* coloff = rowoff + 129;                               // [129]

  prefix_kernel<<<1, 256, 0, stream>>>(il, cl, rowoff, coloff);
  gather_cvt_kernel<<<BI * RR + BT * WW, 256, 0, stream>>>(
      imgs, caps, il, cl, rowoff, coloff, Ab, Bb);
  gemm_kernel<<<36 * 50, 256, 0, stream>>>(Ab, Bb, rowoff, coloff, fg);
  sink_kernel<<<(BI * BT) / 4, 256, 0, stream>>>(fg, il, cl, rowoff, coloff, out);
}